// Round 8
// baseline (292.956 us; speedup 1.0000x reference)
//
#include <hip/hip_runtime.h>
#include <stdint.h>

// ---------- types / helpers ----------
typedef __attribute__((ext_vector_type(8))) short   short8;   // 8 bf16 (4 VGPRs)
typedef __attribute__((ext_vector_type(8))) __bf16  bf16x8;
typedef __attribute__((ext_vector_type(4))) float   floatx4;

__device__ __forceinline__ float bf2f(uint16_t h) {
    union { uint32_t u; float f; } v; v.u = ((uint32_t)h) << 16; return v.f;
}
__device__ __forceinline__ uint16_t f2bf(float f) {
    union { float f; uint32_t u; } v; v.f = f;
    uint32_t u = v.u;
    u += 0x7FFFu + ((u >> 16) & 1u);   // RNE
    return (uint16_t)(u >> 16);
}
__device__ __forceinline__ floatx4 mfma16(short8 a, short8 b, floatx4 c) {
    return __builtin_amdgcn_mfma_f32_16x16x32_bf16(
        __builtin_bit_cast(bf16x8, a), __builtin_bit_cast(bf16x8, b), c, 0, 0, 0);
}
// async global->LDS, 16B per lane
__device__ __forceinline__ void gll16(const short* g, short* l) {
    __builtin_amdgcn_global_load_lds(
        (const __attribute__((address_space(1))) uint32_t*)g,
        (__attribute__((address_space(3))) uint32_t*)l, 16, 0, 0);
}

// ---------- f32 -> bf16 conversion ----------
__global__ void convf(const float* __restrict__ src, short* __restrict__ dst, int n4) {
    int i = blockIdx.x * 256 + threadIdx.x;
    if (i < n4) {
        float4 v = ((const float4*)src)[i];
        ((short4*)dst)[i] = make_short4((short)f2bf(v.x), (short)f2bf(v.y),
                                        (short)f2bf(v.z), (short)f2bf(v.w));
    }
}
__global__ void convb(const float* __restrict__ b0, const float* __restrict__ b1,
                      const float* __restrict__ b2, const float* __restrict__ b3,
                      short* __restrict__ dst) {
    const float* s = (blockIdx.x == 0) ? b0 : (blockIdx.x == 1) ? b1
                   : (blockIdx.x == 2) ? b2 : b3;
    for (int j = threadIdx.x; j < 1024; j += 256)
        dst[blockIdx.x * 1024 + j] = (short)f2bf(s[j]);
}
// er[64][1024] f32 -> ErT[1024][64] bf16
__global__ void ert_kernel(const float* __restrict__ er, short* __restrict__ ErT) {
    int idx = blockIdx.x * 256 + threadIdx.x;      // 65536 total
    int w = idx >> 6, d = idx & 63;
    ErT[idx] = (short)f2bf(er[d * 1024 + w]);
}

// ---------- GEMM body: out = A[M,1024] @ Wt[N,1024]^T + bias (bf16 in) ----------
// tile 128(M) x 64(N), BK=64, 4 waves (2x2), wave tile 64x32  [m97 pattern]
// variant: 0=Q layout [b,h,w,d] bf16, 1=K layout bf16, 2=Vt [b,h,d,w] bf16,
//          3=plain [m,n] FLOAT32 (final output)
__device__ __forceinline__ void gemm_body(
    const short* __restrict__ A, const short* __restrict__ Wt,
    const short* __restrict__ bias, short* __restrict__ dst,
    float* __restrict__ dstf, int variant)
{
    __shared__ short As[128 * 64];
    __shared__ short Bs[64 * 64];
    const int tid  = threadIdx.x;
    const int wid  = tid >> 6;
    const int lane = tid & 63;
    const int m0 = blockIdx.x * 128;
    const int n0 = blockIdx.y * 64;
    const int wm = (wid >> 1) * 64;
    const int wn = (wid & 1) * 32;
    const int lrow = lane & 15;
    const int quad = lane >> 4;
    const int lk   = quad * 8;
    const int srow = lane >> 3;        // 0..7 within an 8-row staging chunk
    const int scol = (lane & 7) * 8;   // 0..56

    floatx4 acc[4][2];
#pragma unroll
    for (int r = 0; r < 4; ++r)
#pragma unroll
        for (int c = 0; c < 2; ++c) acc[r][c] = (floatx4){0.f, 0.f, 0.f, 0.f};

    for (int k0 = 0; k0 < 1024; k0 += 64) {
#pragma unroll
        for (int i = 0; i < 4; ++i) {               // A: 16 chunks of 8 rows x 64 cols
            int q = wid * 4 + i;
            gll16(A + (size_t)(m0 + q * 8 + srow) * 1024 + k0 + scol,
                  &As[q * 512 + lane * 8]);
        }
#pragma unroll
        for (int i = 0; i < 2; ++i) {               // B: 8 chunks
            int q = wid * 2 + i;
            gll16(Wt + (size_t)(n0 + q * 8 + srow) * 1024 + k0 + scol,
                  &Bs[q * 512 + lane * 8]);
        }
        __syncthreads();                            // drains vmcnt (gll) too
#pragma unroll
        for (int ks = 0; ks < 2; ++ks) {
            short8 af[4], bfr[2];
#pragma unroll
            for (int r = 0; r < 4; ++r)
                af[r] = *(const short8*)&As[(wm + r * 16 + lrow) * 64 + ks * 32 + lk];
#pragma unroll
            for (int c = 0; c < 2; ++c)
                bfr[c] = *(const short8*)&Bs[(wn + c * 16 + lrow) * 64 + ks * 32 + lk];
#pragma unroll
            for (int r = 0; r < 4; ++r)
#pragma unroll
                for (int c = 0; c < 2; ++c)
                    acc[r][c] = mfma16(af[r], bfr[c], acc[r][c]);
        }
        __syncthreads();
    }

    // epilogue: C/D layout col=lane&15, row=quad*4+reg
#pragma unroll
    for (int c = 0; c < 2; ++c) {
        int col = n0 + wn + c * 16 + lrow;
        float bv = bf2f((uint16_t)bias[col]);
#pragma unroll
        for (int r = 0; r < 4; ++r) {
#pragma unroll
            for (int g = 0; g < 4; ++g) {
                int m = m0 + wm + r * 16 + quad * 4 + g;
                float fv = acc[r][c][g] + bv;
                if (variant == 3) {                 // FINAL OUTPUT: float32
                    dstf[(size_t)m * 1024 + col] = fv;
                } else if (variant == 2) {          // Vt: [b,h,d=64,w=1024]
                    int bh = (m >> 10) * 16 + (col >> 6);
                    dst[(size_t)bh * 65536 + (size_t)(col & 63) * 1024 + (m & 1023)] =
                        (short)f2bf(fv);
                } else {                            // Q/K: [b,h,w=1024,d=64]
                    int bh = (m >> 10) * 16 + (col >> 6);
                    dst[(size_t)bh * 65536 + (size_t)(m & 1023) * 64 + (col & 63)] =
                        (short)f2bf(fv);
                }
            }
        }
    }
}

__global__ __launch_bounds__(256) void qkv_gemm(
    const short* __restrict__ x,
    const short* __restrict__ Wq, const short* __restrict__ Wk,
    const short* __restrict__ Wv, const short* __restrict__ bqkv,
    short* __restrict__ Qb, short* __restrict__ Kb, short* __restrict__ Vb)
{
    int z = blockIdx.z;
    const short* Wt = (z == 0) ? Wq : (z == 1) ? Wk : Wv;
    short* dst      = (z == 0) ? Qb : (z == 1) ? Kb : Vb;
    gemm_body(x, Wt, bqkv + z * 1024, dst, nullptr, z);
}

__global__ __launch_bounds__(256) void out_gemm(
    const short* __restrict__ AV, const short* __restrict__ Wo,
    const short* __restrict__ bo, float* __restrict__ out)
{
    gemm_body(AV, Wo, bo, nullptr, out, 3);
}

// ---------- flash attention ----------
// S[i,j] = (q_i.k_j + e_i.q_j)/32, e_i = er[:,i]; softmax over j; O = P V
// grid (16 heads, 4 batch, 8 i-tiles): linear%8 = h%8 -> all blocks of a head
// share an XCD (K/Q/V slice ~3MB fits its 4MB L2).
// block 256 = 4 waves, wave = 32 q-rows. LDS 40KB -> 4 blocks/CU.
__global__ __launch_bounds__(256, 4) void attn_kernel(
    const short* __restrict__ Q, const short* __restrict__ K,
    const short* __restrict__ Vt, const short* __restrict__ ErT,
    short* __restrict__ AV)
{
    __shared__ short Ks [64 * 64];    // K rows j0..j0+63
    __shared__ short Qks[64 * 64];    // Q rows j0..j0+63 (bias key side)
    __shared__ short Vs [64 * 64];    // V^T [d][j]
    __shared__ short Ps [128 * 64];   // P [i][j]
    const int tid  = threadIdx.x;
    const int wid  = tid >> 6;
    const int lane = tid & 63;
    const int lrow = lane & 15;
    const int quad = lane >> 4;
    const int lk   = quad * 8;
    const int srow = lane >> 3;        // staging: 8 rows x 64 cols per chunk
    const int scol = (lane & 7) * 8;
    const int h = blockIdx.x, b = blockIdx.y;
    const int bh = b * 16 + h;
    const int i0 = blockIdx.z * 128;
    const short* Qbh = Q  + (size_t)bh * 65536;
    const short* Kbh = K  + (size_t)bh * 65536;
    const short* Vbh = Vt + (size_t)bh * 65536;

    // Qaug A-frags loaded DIRECTLY from global (one-time; A-layout is row-major):
    // lane holds A[m = lrow][k = quad*8 + 0..7]; kk<2 from Q, kk>=2 from ErT
    short8 qa[2][4];
#pragma unroll
    for (int r = 0; r < 2; ++r) {
        int row = i0 + wid * 32 + r * 16 + lrow;
#pragma unroll
        for (int kk = 0; kk < 2; ++kk) {
            qa[r][kk]     = *(const short8*)&Qbh[(size_t)row * 64 + kk * 32 + lk];
            qa[r][kk + 2] = *(const short8*)&ErT[(size_t)row * 64 + kk * 32 + lk];
        }
    }

    float mrun[2][4], lrun[2][4];
    floatx4 oacc[2][4];
#pragma unroll
    for (int r = 0; r < 2; ++r)
#pragma unroll
        for (int g = 0; g < 4; ++g) { mrun[r][g] = -1e30f; lrun[r][g] = 0.f; }
#pragma unroll
    for (int r = 0; r < 2; ++r)
#pragma unroll
        for (int c = 0; c < 4; ++c) oacc[r][c] = (floatx4){0.f, 0.f, 0.f, 0.f};

    for (int jt = 0; jt < 16; ++jt) {
        int j0 = jt * 64;
        // stage Ks/Qks/Vs: 8 chunks each of 8 rows x 64 cols
#pragma unroll
        for (int ii = 0; ii < 2; ++ii) {
            int q = wid * 2 + ii;
            gll16(Kbh + (size_t)(j0 + q * 8 + srow) * 64 + scol,   &Ks [q * 512 + lane * 8]);
            gll16(Qbh + (size_t)(j0 + q * 8 + srow) * 64 + scol,   &Qks[q * 512 + lane * 8]);
            gll16(Vbh + (size_t)(q * 8 + srow) * 1024 + j0 + scol, &Vs [q * 512 + lane * 8]);
        }
        __syncthreads();   // (a) staging complete

        // S-MFMA: Kaug B-frags: kk<2 from Ks, kk>=2 from Qks
        floatx4 s[2][4];
#pragma unroll
        for (int r = 0; r < 2; ++r)
#pragma unroll
            for (int c = 0; c < 4; ++c) s[r][c] = (floatx4){0.f, 0.f, 0.f, 0.f};
#pragma unroll
        for (int kk = 0; kk < 4; ++kk) {
            short8 kb[4];
#pragma unroll
            for (int c = 0; c < 4; ++c)
                kb[c] = (kk < 2)
                    ? *(const short8*)&Ks [(c * 16 + lrow) * 64 + kk * 32 + lk]
                    : *(const short8*)&Qks[(c * 16 + lrow) * 64 + (kk - 2) * 32 + lk];
#pragma unroll
            for (int r = 0; r < 2; ++r)
#pragma unroll
                for (int c = 0; c < 4; ++c)
                    s[r][c] = mfma16(qa[r][kk], kb[c], s[r][c]);
        }

        // online softmax (row stats shared across the quad's 16 lanes via shfl)
        const float sc = 1.0f / 32.0f;
        float alpha_[2][4];
#pragma unroll
        for (int r = 0; r < 2; ++r) {
#pragma unroll
            for (int g = 0; g < 4; ++g) {
                float mx = fmaxf(fmaxf(s[r][0][g], s[r][1][g]), fmaxf(s[r][2][g], s[r][3][g]));
#pragma unroll
                for (int d = 1; d < 16; d <<= 1) mx = fmaxf(mx, __shfl_xor(mx, d, 64));
                mx *= sc;
                float mn = fmaxf(mrun[r][g], mx);
                float al = __expf(mrun[r][g] - mn);
                float rs = 0.f;
#pragma unroll
                for (int c = 0; c < 4; ++c) {
                    float p = __expf(s[r][c][g] * sc - mn);
                    s[r][c][g] = p;
                    rs += p;
                }
#pragma unroll
                for (int d = 1; d < 16; d <<= 1) rs += __shfl_xor(rs, d, 64);
                lrun[r][g] = lrun[r][g] * al + rs;
                mrun[r][g] = mn;
                alpha_[r][g] = al;
            }
        }
#pragma unroll
        for (int r = 0; r < 2; ++r)
#pragma unroll
            for (int c = 0; c < 4; ++c)
#pragma unroll
                for (int g = 0; g < 4; ++g) oacc[r][c][g] *= alpha_[r][g];

        // write P (bf16) to Ps rows wid*32..+31 (WAVE-PRIVATE: same wave writes
        // then reads; DS pipe is in-order per wave; rounds 2 vs 3 bit-identical
        // proved no barrier needed). Compiler-only fence pins ordering.
#pragma unroll
        for (int r = 0; r < 2; ++r)
#pragma unroll
            for (int c = 0; c < 4; ++c)
#pragma unroll
                for (int g = 0; g < 4; ++g)
                    Ps[(wid * 32 + r * 16 + quad * 4 + g) * 64 + c * 16 + lrow] =
                        (short)f2bf(s[r][c][g]);
        __asm__ __volatile__("" ::: "memory");

        // PV-MFMA: k = 64 j's
#pragma unroll
        for (int kk = 0; kk < 2; ++kk) {
            short8 pa[2], vb[4];
#pragma unroll
            for (int r = 0; r < 2; ++r)
                pa[r] = *(const short8*)&Ps[(wid * 32 + r * 16 + lrow) * 64 + kk * 32 + lk];
#pragma unroll
            for (int c = 0; c < 4; ++c)
                vb[c] = *(const short8*)&Vs[(c * 16 + lrow) * 64 + kk * 32 + lk];
#pragma unroll
            for (int r = 0; r < 2; ++r)
#pragma unroll
                for (int c = 0; c < 4; ++c)
                    oacc[r][c] = mfma16(pa[r], vb[c], oacc[r][c]);
        }
        __syncthreads();   // (c) all reads done before next staging
    }

    // epilogue: AV[b, w=i, c=h*64+d] bf16
#pragma unroll
    for (int r = 0; r < 2; ++r)
#pragma unroll
        for (int c = 0; c < 4; ++c)
#pragma unroll
            for (int g = 0; g < 4; ++g) {
                int row = i0 + wid * 32 + r * 16 + quad * 4 + g;
                int colc = h * 64 + c * 16 + lrow;
                AV[((size_t)b * 1024 + row) * 1024 + colc] = (short)f2bf(oacc[r][c][g] / lrun[r][g]);
            }
}

// ---------- launcher ----------
extern "C" void kernel_launch(void* const* d_in, const int* in_sizes, int n_in,
                              void* d_out, int out_size, void* d_ws, size_t ws_size,
                              hipStream_t stream) {
    const float* x  = (const float*)d_in[0];
    const float* Wq = (const float*)d_in[1];
    const float* bq = (const float*)d_in[2];
    const float* Wk = (const float*)d_in[3];
    const float* bk = (const float*)d_in[4];
    const float* Wv = (const float*)d_in[5];
    const float* bv = (const float*)d_in[6];
    const float* Wo = (const float*)d_in[7];
    const float* bo = (const float*)d_in[8];
    const float* er = (const float*)d_in[9];
    float* out = (float*)d_out;       // float32 output: 4M floats = 16 MB

    const size_t M1 = 1u << 20;
    short* ws   = (short*)d_ws;
    short* xb   = (short*)d_out;      // bf16 x in d_out's first 8MB; dead before out_gemm
    short* Qb   = ws;                 // 4M  [b,h,w,d]
    short* Kb   = ws + 4 * M1;        // 4M  [b,h,w,d]
    short* Vb   = ws + 8 * M1;        // 4M  [b,h,d,w]
    short* AVb  = ws + 12 * M1;       // 4M  [b,w,c]
    short* Wqb  = ws + 16 * M1;       // 1M
    short* Wkb  = ws + 17 * M1;       // 1M
    short* Wvb  = ws + 18 * M1;       // 1M
    short* Wob  = ws + 19 * M1;       // 1M
    short* ball = ws + 20 * M1;       // 4x1024 (bq,bk,bv,bo)
    short* ErT  = ws + 20 * M1 + 4096; // 65536 [w,d]
    // total ws requirement: ~40.14 MB

    hipLaunchKernelGGL(convf, dim3(4096), dim3(256), 0, stream, x,  xb,  1u << 20);
    hipLaunchKernelGGL(convf, dim3(1024), dim3(256), 0, stream, Wq, Wqb, 1u << 18);
    hipLaunchKernelGGL(convf, dim3(1024), dim3(256), 0, stream, Wk, Wkb, 1u << 18);
    hipLaunchKernelGGL(convf, dim3(1024), dim3(256), 0, stream, Wv, Wvb, 1u << 18);
    hipLaunchKernelGGL(convf, dim3(1024), dim3(256), 0, stream, Wo, Wob, 1u << 18);
    hipLaunchKernelGGL(convb, dim3(4), dim3(256), 0, stream, bq, bk, bv, bo, ball);
    hipLaunchKernelGGL(ert_kernel, dim3(256), dim3(256), 0, stream, er, ErT);

    hipLaunchKernelGGL(qkv_gemm, dim3(32, 16, 3), dim3(256), 0, stream,
                       xb, Wqb, Wkb, Wvb, ball, Qb, Kb, Vb);
    hipLaunchKernelGGL(attn_kernel, dim3(16, 4, 8), dim3(256), 0, stream,
                       Qb, Kb, Vb, ErT, AVb);
    hipLaunchKernelGGL(out_gemm, dim3(32, 16), dim3(256), 0, stream, AVb, Wob, ball + 3072, out);
}

// Round 9
// 260.350 us; speedup vs baseline: 1.1252x; 1.1252x over previous
//
#include <hip/hip_runtime.h>
#include <stdint.h>

// ---------- types / helpers ----------
typedef __attribute__((ext_vector_type(8))) short   short8;   // 8 bf16 (4 VGPRs)
typedef __attribute__((ext_vector_type(8))) __bf16  bf16x8;
typedef __attribute__((ext_vector_type(4))) float   floatx4;

__device__ __forceinline__ float bf2f(uint16_t h) {
    union { uint32_t u; float f; } v; v.u = ((uint32_t)h) << 16; return v.f;
}
__device__ __forceinline__ uint16_t f2bf(float f) {
    union { float f; uint32_t u; } v; v.f = f;
    uint32_t u = v.u;
    u += 0x7FFFu + ((u >> 16) & 1u);   // RNE
    return (uint16_t)(u >> 16);
}
__device__ __forceinline__ floatx4 mfma16(short8 a, short8 b, floatx4 c) {
    return __builtin_amdgcn_mfma_f32_16x16x32_bf16(
        __builtin_bit_cast(bf16x8, a), __builtin_bit_cast(bf16x8, b), c, 0, 0, 0);
}
// async global->LDS, 16B per lane
__device__ __forceinline__ void gll16(const short* g, short* l) {
    __builtin_amdgcn_global_load_lds(
        (const __attribute__((address_space(1))) uint32_t*)g,
        (__attribute__((address_space(3))) uint32_t*)l, 16, 0, 0);
}

// ---------- f32 -> bf16 conversion ----------
__global__ void convf(const float* __restrict__ src, short* __restrict__ dst, int n4) {
    int i = blockIdx.x * 256 + threadIdx.x;
    if (i < n4) {
        float4 v = ((const float4*)src)[i];
        ((short4*)dst)[i] = make_short4((short)f2bf(v.x), (short)f2bf(v.y),
                                        (short)f2bf(v.z), (short)f2bf(v.w));
    }
}
__global__ void convb(const float* __restrict__ b0, const float* __restrict__ b1,
                      const float* __restrict__ b2, const float* __restrict__ b3,
                      short* __restrict__ dst) {
    const float* s = (blockIdx.x == 0) ? b0 : (blockIdx.x == 1) ? b1
                   : (blockIdx.x == 2) ? b2 : b3;
    for (int j = threadIdx.x; j < 1024; j += 256)
        dst[blockIdx.x * 1024 + j] = (short)f2bf(s[j]);
}
// er[64][1024] f32 -> ErT[1024][64] bf16
__global__ void ert_kernel(const float* __restrict__ er, short* __restrict__ ErT) {
    int idx = blockIdx.x * 256 + threadIdx.x;      // 65536 total
    int w = idx >> 6, d = idx & 63;
    ErT[idx] = (short)f2bf(er[d * 1024 + w]);
}

// ---------- GEMM body: out = A[M,1024] @ Wt[N,1024]^T + bias (bf16 in) ----------
// tile 128(M) x 64(N), BK=64, 4 waves (2x2), wave tile 64x32  [m97 pattern]
// variant: 0=Q layout [b,h,w,d] bf16, 1=K layout bf16, 2=Vt [b,h,d,w] bf16,
//          3=plain [m,n] FLOAT32 (final output)
__device__ __forceinline__ void gemm_body(
    const short* __restrict__ A, const short* __restrict__ Wt,
    const short* __restrict__ bias, short* __restrict__ dst,
    float* __restrict__ dstf, int variant)
{
    __shared__ short As[128 * 64];
    __shared__ short Bs[64 * 64];
    const int tid  = threadIdx.x;
    const int wid  = tid >> 6;
    const int lane = tid & 63;
    const int m0 = blockIdx.x * 128;
    const int n0 = blockIdx.y * 64;
    const int wm = (wid >> 1) * 64;
    const int wn = (wid & 1) * 32;
    const int lrow = lane & 15;
    const int quad = lane >> 4;
    const int lk   = quad * 8;
    const int srow = lane >> 3;        // 0..7 within an 8-row staging chunk
    const int scol = (lane & 7) * 8;   // 0..56

    floatx4 acc[4][2];
#pragma unroll
    for (int r = 0; r < 4; ++r)
#pragma unroll
        for (int c = 0; c < 2; ++c) acc[r][c] = (floatx4){0.f, 0.f, 0.f, 0.f};

    for (int k0 = 0; k0 < 1024; k0 += 64) {
#pragma unroll
        for (int i = 0; i < 4; ++i) {               // A: 16 chunks of 8 rows x 64 cols
            int q = wid * 4 + i;
            gll16(A + (size_t)(m0 + q * 8 + srow) * 1024 + k0 + scol,
                  &As[q * 512 + lane * 8]);
        }
#pragma unroll
        for (int i = 0; i < 2; ++i) {               // B: 8 chunks
            int q = wid * 2 + i;
            gll16(Wt + (size_t)(n0 + q * 8 + srow) * 1024 + k0 + scol,
                  &Bs[q * 512 + lane * 8]);
        }
        __syncthreads();                            // drains vmcnt (gll) too
#pragma unroll
        for (int ks = 0; ks < 2; ++ks) {
            short8 af[4], bfr[2];
#pragma unroll
            for (int r = 0; r < 4; ++r)
                af[r] = *(const short8*)&As[(wm + r * 16 + lrow) * 64 + ks * 32 + lk];
#pragma unroll
            for (int c = 0; c < 2; ++c)
                bfr[c] = *(const short8*)&Bs[(wn + c * 16 + lrow) * 64 + ks * 32 + lk];
#pragma unroll
            for (int r = 0; r < 4; ++r)
#pragma unroll
                for (int c = 0; c < 2; ++c)
                    acc[r][c] = mfma16(af[r], bfr[c], acc[r][c]);
        }
        __syncthreads();
    }

    // epilogue: C/D layout col=lane&15, row=quad*4+reg
#pragma unroll
    for (int c = 0; c < 2; ++c) {
        int col = n0 + wn + c * 16 + lrow;
        float bv = bf2f((uint16_t)bias[col]);
#pragma unroll
        for (int r = 0; r < 4; ++r) {
#pragma unroll
            for (int g = 0; g < 4; ++g) {
                int m = m0 + wm + r * 16 + quad * 4 + g;
                float fv = acc[r][c][g] + bv;
                if (variant == 3) {                 // FINAL OUTPUT: float32
                    dstf[(size_t)m * 1024 + col] = fv;
                } else if (variant == 2) {          // Vt: [b,h,d=64,w=1024]
                    int bh = (m >> 10) * 16 + (col >> 6);
                    dst[(size_t)bh * 65536 + (size_t)(col & 63) * 1024 + (m & 1023)] =
                        (short)f2bf(fv);
                } else {                            // Q/K: [b,h,w=1024,d=64]
                    int bh = (m >> 10) * 16 + (col >> 6);
                    dst[(size_t)bh * 65536 + (size_t)(m & 1023) * 64 + (col & 63)] =
                        (short)f2bf(fv);
                }
            }
        }
    }
}

__global__ __launch_bounds__(256) void qkv_gemm(
    const short* __restrict__ x,
    const short* __restrict__ Wq, const short* __restrict__ Wk,
    const short* __restrict__ Wv, const short* __restrict__ bqkv,
    short* __restrict__ Qb, short* __restrict__ Kb, short* __restrict__ Vb)
{
    int z = blockIdx.z;
    const short* Wt = (z == 0) ? Wq : (z == 1) ? Wk : Wv;
    short* dst      = (z == 0) ? Qb : (z == 1) ? Kb : Vb;
    gemm_body(x, Wt, bqkv + z * 1024, dst, nullptr, z);
}

__global__ __launch_bounds__(256) void out_gemm(
    const short* __restrict__ AV, const short* __restrict__ Wo,
    const short* __restrict__ bo, float* __restrict__ out)
{
    gemm_body(AV, Wo, bo, nullptr, out, 3);
}

// ---------- flash attention ----------
// S[i,j] = (q_i.k_j + e_i.q_j)/32, e_i = er[:,i]; softmax over j; O = P V
// grid (16 heads, 4 batch, 8 i-tiles) = 512 blocks = 2 blocks/CU (grid-limited)
// -> block = 512 threads (8 waves x 16 q-rows = 128-row tile) for 16 waves/CU.
// linear%8 = h%8 -> all blocks of a head share an XCD (~3MB slice fits 4MB L2).
// NO min-waves launch bound (round 8: (256,4) forced VGPR=64 -> 83MB spills).
#define PSTR 72   // Ps row stride (shorts): 16B-aligned, quad stride 144B kills 8-way bank conflict
__global__ __launch_bounds__(512) void attn_kernel(
    const short* __restrict__ Q, const short* __restrict__ K,
    const short* __restrict__ Vt, const short* __restrict__ ErT,
    short* __restrict__ AV)
{
    __shared__ short Ks [64 * 64];    // K rows j0..j0+63
    __shared__ short Qks[64 * 64];    // Q rows j0..j0+63 (bias key side)
    __shared__ short Vs [64 * 64];    // V^T [d][j]
    __shared__ short Ps [128 * PSTR]; // P [i][j], padded stride
    const int tid  = threadIdx.x;
    const int wid  = tid >> 6;        // 0..7
    const int lane = tid & 63;
    const int lrow = lane & 15;
    const int quad = lane >> 4;
    const int lk   = quad * 8;
    const int srow = lane >> 3;        // staging: 8 rows x 64 cols per chunk
    const int scol = (lane & 7) * 8;
    const int h = blockIdx.x, b = blockIdx.y;
    const int bh = b * 16 + h;
    const int i0 = blockIdx.z * 128;
    const int wrow = wid * 16;         // this wave's 16 q-rows (local)
    const short* Qbh = Q  + (size_t)bh * 65536;
    const short* Kbh = K  + (size_t)bh * 65536;
    const short* Vbh = Vt + (size_t)bh * 65536;

    // Qaug A-frags loaded DIRECTLY from global (one-time; row-major A-layout):
    // lane holds A[m=lrow][k=quad*8+0..7]; kk<2 from Q, kk>=2 from ErT
    short8 qa[4];
    {
        int row = i0 + wrow + lrow;
#pragma unroll
        for (int kk = 0; kk < 2; ++kk) {
            qa[kk]     = *(const short8*)&Qbh[(size_t)row * 64 + kk * 32 + lk];
            qa[kk + 2] = *(const short8*)&ErT[(size_t)row * 64 + kk * 32 + lk];
        }
    }

    float mrun[4], lrun[4];
    floatx4 oacc[4];
#pragma unroll
    for (int g = 0; g < 4; ++g) { mrun[g] = -1e30f; lrun[g] = 0.f; }
#pragma unroll
    for (int c = 0; c < 4; ++c) oacc[c] = (floatx4){0.f, 0.f, 0.f, 0.f};

    for (int jt = 0; jt < 16; ++jt) {
        int j0 = jt * 64;
        // stage Ks/Qks/Vs: 8 chunks each; wave wid stages chunk wid of each array
        gll16(Kbh + (size_t)(j0 + wid * 8 + srow) * 64 + scol,   &Ks [wid * 512 + lane * 8]);
        gll16(Qbh + (size_t)(j0 + wid * 8 + srow) * 64 + scol,   &Qks[wid * 512 + lane * 8]);
        gll16(Vbh + (size_t)(wid * 8 + srow) * 1024 + j0 + scol, &Vs [wid * 512 + lane * 8]);
        __syncthreads();   // (a) staging complete

        // S-MFMA: Kaug B-frags: kk<2 from Ks, kk>=2 from Qks
        floatx4 s[4];
#pragma unroll
        for (int c = 0; c < 4; ++c) s[c] = (floatx4){0.f, 0.f, 0.f, 0.f};
#pragma unroll
        for (int kk = 0; kk < 4; ++kk) {
            short8 kb[4];
#pragma unroll
            for (int c = 0; c < 4; ++c)
                kb[c] = (kk < 2)
                    ? *(const short8*)&Ks [(c * 16 + lrow) * 64 + kk * 32 + lk]
                    : *(const short8*)&Qks[(c * 16 + lrow) * 64 + (kk - 2) * 32 + lk];
#pragma unroll
            for (int c = 0; c < 4; ++c)
                s[c] = mfma16(qa[kk], kb[c], s[c]);
        }

        // online softmax (row stats shared across the quad's 16 lanes via shfl)
        const float sc = 1.0f / 32.0f;
        float alpha_[4];
#pragma unroll
        for (int g = 0; g < 4; ++g) {
            float mx = fmaxf(fmaxf(s[0][g], s[1][g]), fmaxf(s[2][g], s[3][g]));
#pragma unroll
            for (int d = 1; d < 16; d <<= 1) mx = fmaxf(mx, __shfl_xor(mx, d, 64));
            mx *= sc;
            float mn = fmaxf(mrun[g], mx);
            float al = __expf(mrun[g] - mn);
            float rs = 0.f;
#pragma unroll
            for (int c = 0; c < 4; ++c) {
                float p = __expf(s[c][g] * sc - mn);
                s[c][g] = p;
                rs += p;
            }
#pragma unroll
            for (int d = 1; d < 16; d <<= 1) rs += __shfl_xor(rs, d, 64);
            lrun[g] = lrun[g] * al + rs;
            mrun[g] = mn;
            alpha_[g] = al;
        }
#pragma unroll
        for (int c = 0; c < 4; ++c)
#pragma unroll
            for (int g = 0; g < 4; ++g) oacc[c][g] *= alpha_[g];

        // write P (bf16) to Ps rows wrow..wrow+15 (WAVE-PRIVATE; DS in-order per
        // wave — rounds 2 vs 3 bit-identical proved no barrier needed here)
#pragma unroll
        for (int c = 0; c < 4; ++c)
#pragma unroll
            for (int g = 0; g < 4; ++g)
                Ps[(wrow + quad * 4 + g) * PSTR + c * 16 + lrow] = (short)f2bf(s[c][g]);
        __asm__ __volatile__("" ::: "memory");

        // PV-MFMA: k = 64 j's
#pragma unroll
        for (int kk = 0; kk < 2; ++kk) {
            short8 pa, vb[4];
            pa = *(const short8*)&Ps[(wrow + lrow) * PSTR + kk * 32 + lk];
#pragma unroll
            for (int c = 0; c < 4; ++c)
                vb[c] = *(const short8*)&Vs[(c * 16 + lrow) * 64 + kk * 32 + lk];
#pragma unroll
            for (int c = 0; c < 4; ++c)
                oacc[c] = mfma16(pa, vb[c], oacc[c]);
        }
        __syncthreads();   // (b) all reads done before next staging
    }

    // epilogue: AV[b, w=i, c=h*64+d] bf16
#pragma unroll
    for (int c = 0; c < 4; ++c)
#pragma unroll
        for (int g = 0; g < 4; ++g) {
            int row = i0 + wrow + quad * 4 + g;
            int colc = h * 64 + c * 16 + lrow;
            AV[((size_t)b * 1024 + row) * 1024 + colc] = (short)f2bf(oacc[c][g] / lrun[g]);
        }
}

// ---------- launcher ----------
extern "C" void kernel_launch(void* const* d_in, const int* in_sizes, int n_in,
                              void* d_out, int out_size, void* d_ws, size_t ws_size,
                              hipStream_t stream) {
    const float* x  = (const float*)d_in[0];
    const float* Wq = (const float*)d_in[1];
    const float* bq = (const float*)d_in[2];
    const float* Wk = (const float*)d_in[3];
    const float* bk = (const float*)d_in[4];
    const float* Wv = (const float*)d_in[5];
    const float* bv = (const float*)d_in[6];
    const float* Wo = (const float*)d_in[7];
    const float* bo = (const float*)d_in[8];
    const float* er = (const float*)d_in[9];
    float* out = (float*)d_out;       // float32 output: 4M floats = 16 MB

    const size_t M1 = 1u << 20;
    short* ws   = (short*)d_ws;
    short* xb   = (short*)d_out;      // bf16 x in d_out's first 8MB; dead before out_gemm
    short* Qb   = ws;                 // 4M  [b,h,w,d]
    short* Kb   = ws + 4 * M1;        // 4M  [b,h,w,d]
    short* Vb   = ws + 8 * M1;        // 4M  [b,h,d,w]
    short* AVb  = ws + 12 * M1;       // 4M  [b,w,c]
    short* Wqb  = ws + 16 * M1;       // 1M
    short* Wkb  = ws + 17 * M1;       // 1M
    short* Wvb  = ws + 18 * M1;       // 1M
    short* Wob  = ws + 19 * M1;       // 1M
    short* ball = ws + 20 * M1;       // 4x1024 (bq,bk,bv,bo)
    short* ErT  = ws + 20 * M1 + 4096; // 65536 [w,d]
    // total ws requirement: ~40.14 MB

    hipLaunchKernelGGL(convf, dim3(4096), dim3(256), 0, stream, x,  xb,  1u << 20);
    hipLaunchKernelGGL(convf, dim3(1024), dim3(256), 0, stream, Wq, Wqb, 1u << 18);
    hipLaunchKernelGGL(convf, dim3(1024), dim3(256), 0, stream, Wk, Wkb, 1u << 18);
    hipLaunchKernelGGL(convf, dim3(1024), dim3(256), 0, stream, Wv, Wvb, 1u << 18);
    hipLaunchKernelGGL(convf, dim3(1024), dim3(256), 0, stream, Wo, Wob, 1u << 18);
    hipLaunchKernelGGL(convb, dim3(4), dim3(256), 0, stream, bq, bk, bv, bo, ball);
    hipLaunchKernelGGL(ert_kernel, dim3(256), dim3(256), 0, stream, er, ErT);

    hipLaunchKernelGGL(qkv_gemm, dim3(32, 16, 3), dim3(256), 0, stream,
                       xb, Wqb, Wkb, Wvb, ball, Qb, Kb, Vb);
    hipLaunchKernelGGL(attn_kernel, dim3(16, 4, 8), dim3(512), 0, stream,
                       Qb, Kb, Vb, ErT, AVb);
    hipLaunchKernelGGL(out_gemm, dim3(32, 16), dim3(256), 0, stream, AVb, Wob, ball + 3072, out);
}